// Round 9
// baseline (95.205 us; speedup 1.0000x reference)
//
#include <hip/hip_runtime.h>
#include <cstddef>

#define Hn 1024
#define Vn 32000
#define Sn 4096
#define CSHIFT 20.0f

__device__ __forceinline__ float wave_reduce_sum(float v) {
#pragma unroll
    for (int o = 32; o > 0; o >>= 1) v += __shfl_down(v, o, 64);
    return v;
}

// ws layout (floats):
// [0,1024)      h
// [1024,2048)   raw ctx (unnormalized, atomic target, zeroed by k_gru blk0)
// [2048,3072)   v = attn_w^T h
// [3072,7168)   escore (e^(s-CSHIFT))
// [7168]        denom (atomic target, zeroed by k_gru)

// out-head h-half: out[row] = out_w[row,0:1024].h + out_b[row]  (4 rows/block, 4KB LDS)
__device__ __forceinline__ void out_h_rows(const float* __restrict__ out_w,
                                           const float* __restrict__ out_b,
                                           const float* __restrict__ ws_h,
                                           float* __restrict__ out,
                                           int row_base, int t)
{
    __shared__ float c[Hn];
    ((float4*)c)[t] = ((const float4*)ws_h)[t];
    __syncthreads();
    const int wv = t >> 6, lane = t & 63;
    const int row = row_base + wv;
    const float* w = out_w + (size_t)row * (2 * Hn);
    float acc = 0.f;
#pragma unroll
    for (int k = 0; k < 4; ++k) {
        const int idx = k * 256 + lane * 4;
        const float4 w4 = *(const float4*)(w + idx);
        acc += w4.x * c[idx] + w4.y * c[idx + 1] + w4.z * c[idx + 2] + w4.w * c[idx + 3];
    }
    acc = wave_reduce_sum(acc);
    if (lane == 0) out[row] = acc + out_b[row];
}

// ---------------- K1: GRU cell -> h (1024 blocks, block per output) ----------------
__global__ __launch_bounds__(256) void k_gru(const int* __restrict__ word,
                                             const float* __restrict__ emb,
                                             const float* __restrict__ h0,
                                             const float* __restrict__ w_ih,
                                             const float* __restrict__ w_hh,
                                             const float* __restrict__ b_ih,
                                             const float* __restrict__ b_hh,
                                             float* __restrict__ ws_h,
                                             float* __restrict__ ws_ctx,
                                             float* __restrict__ ws_denom,
                                             float* __restrict__ out_h)
{
    const int k = blockIdx.x;
    const int t = threadIdx.x;

    if (k == 0) {                       // zero atomic targets for this call
#pragma unroll
        for (int i = 0; i < 4; ++i) ws_ctx[t + i * 256] = 0.f;
        if (t == 0) ws_denom[0] = 0.f;
    }

    const float* x = emb + (size_t)word[0] * Hn;
    const float4 xv = ((const float4*)x)[t];
    const float4 hv = ((const float4*)h0)[t];

    float acc[6];
    const float* rows[6] = {
        w_ih + (size_t)k * Hn, w_ih + (size_t)(k + Hn) * Hn, w_ih + (size_t)(k + 2 * Hn) * Hn,
        w_hh + (size_t)k * Hn, w_hh + (size_t)(k + Hn) * Hn, w_hh + (size_t)(k + 2 * Hn) * Hn
    };
#pragma unroll
    for (int g = 0; g < 6; ++g) {
        const float4 w = ((const float4*)rows[g])[t];
        const float4 vv = (g < 3) ? xv : hv;
        acc[g] = w.x * vv.x + w.y * vv.y + w.z * vv.z + w.w * vv.w;
    }

    __shared__ float red[6][4];
    const int wv = t >> 6, lane = t & 63;
#pragma unroll
    for (int g = 0; g < 6; ++g) {
        const float s = wave_reduce_sum(acc[g]);
        if (lane == 0) red[g][wv] = s;
    }
    __syncthreads();
    if (t == 0) {
        float g0 = red[0][0] + red[0][1] + red[0][2] + red[0][3] + b_ih[k];
        float g1 = red[1][0] + red[1][1] + red[1][2] + red[1][3] + b_ih[k + Hn];
        float g2 = red[2][0] + red[2][1] + red[2][2] + red[2][3] + b_ih[k + 2 * Hn];
        float g3 = red[3][0] + red[3][1] + red[3][2] + red[3][3] + b_hh[k];
        float g4 = red[4][0] + red[4][1] + red[4][2] + red[4][3] + b_hh[k + Hn];
        float g5 = red[5][0] + red[5][1] + red[5][2] + red[5][3] + b_hh[k + 2 * Hn];
        float r = 1.f / (1.f + expf(-(g0 + g3)));
        float z = 1.f / (1.f + expf(-(g1 + g4)));
        float n = tanhf(g2 + r * g5);
        float hk = (1.f - z) * n + z * h0[k];
        ws_h[k]  = hk;
        out_h[k] = hk;
    }
}

// ------- K2: attnv (blocks 0..63) ∥ out_h rows [0,10668) -------
__global__ __launch_bounds__(256) void k_a(const float* __restrict__ attn_w,
                                           const float* __restrict__ ws_h,
                                           float* __restrict__ v,
                                           const float* __restrict__ out_w,
                                           const float* __restrict__ out_b,
                                           float* __restrict__ out)
{
    const int t = threadIdx.x, bid = blockIdx.x;
    if (bid < 64) {
        const int tj = t >> 4, tk = t & 15;
        const int k = bid * 16 + tk;
        float acc = 0.f;
        for (int j = tj; j < Hn; j += 16)
            acc += attn_w[(size_t)j * Hn + k] * ws_h[j];
        __shared__ float p[16][17];
        p[tj][tk] = acc;
        __syncthreads();
        if (t < 16) {
            float s = 0.f;
#pragma unroll
            for (int j = 0; j < 16; ++j) s += p[j][t];
            v[bid * 16 + t] = s;
        }
    } else {
        out_h_rows(out_w, out_b, ws_h, out, (bid - 64) * 4, t);
    }
}

// ------- K3: fused scores+e^s+ctx (blocks 0..127, 32 rows each, 20KB LDS)
//         ∥ out_h rows [10668,21336) -------
__global__ __launch_bounds__(256) void k_sctx(const float* __restrict__ enc,
                                              const float* __restrict__ ws_v,
                                              float* __restrict__ escore,
                                              float* __restrict__ ctx,
                                              float* __restrict__ denom,
                                              const float* __restrict__ ws_h,
                                              const float* __restrict__ out_w,
                                              const float* __restrict__ out_b,
                                              float* __restrict__ out)
{
    const int t = threadIdx.x, bid = blockIdx.x;
    if (bid < 128) {
        __shared__ float rows[4][Hn];    // 16 KB
        __shared__ float vsh[Hn];        // 4 KB
        __shared__ float esl[4];
        const int wv = t >> 6, lane = t & 63;
        const int s0 = bid * 32;

        ((float4*)vsh)[t] = ((const float4*)ws_v)[t];

        float4 acc = make_float4(0.f, 0.f, 0.f, 0.f);
        float dsum = 0.f;

        for (int g = 0; g < 8; ++g) {
            __syncthreads();            // rows/esl from previous group fully consumed
            const float* erow = enc + (size_t)(s0 + g * 4) * Hn;
#pragma unroll
            for (int r = 0; r < 4; ++r)
                ((float4*)rows[r])[t] = ((const float4*)(erow + (size_t)r * Hn))[t];
            __syncthreads();

            // wave wv dots row wv
            float a = 0.f;
#pragma unroll
            for (int k = 0; k < 4; ++k) {
                const int idx = k * 256 + lane * 4;
                const float4 e = *(const float4*)&rows[wv][idx];
                a += e.x * vsh[idx] + e.y * vsh[idx + 1] + e.z * vsh[idx + 2] + e.w * vsh[idx + 3];
            }
            a = wave_reduce_sum(a);
            if (lane == 0) {
                const float ev = expf(a - CSHIFT);
                esl[wv] = ev;
                escore[s0 + g * 4 + wv] = ev;
            }
            __syncthreads();

            const float e0 = esl[0], e1 = esl[1], e2 = esl[2], e3 = esl[3];
            dsum += e0 + e1 + e2 + e3;
            const float4 r0 = ((const float4*)rows[0])[t];
            const float4 r1 = ((const float4*)rows[1])[t];
            const float4 r2 = ((const float4*)rows[2])[t];
            const float4 r3 = ((const float4*)rows[3])[t];
            acc.x += e0 * r0.x + e1 * r1.x + e2 * r2.x + e3 * r3.x;
            acc.y += e0 * r0.y + e1 * r1.y + e2 * r2.y + e3 * r3.y;
            acc.z += e0 * r0.z + e1 * r1.z + e2 * r2.z + e3 * r3.z;
            acc.w += e0 * r0.w + e1 * r1.w + e2 * r2.w + e3 * r3.w;
        }
        atomicAdd(&ctx[t * 4],     acc.x);
        atomicAdd(&ctx[t * 4 + 1], acc.y);
        atomicAdd(&ctx[t * 4 + 2], acc.z);
        atomicAdd(&ctx[t * 4 + 3], acc.w);
        if (t == 0) atomicAdd(denom, dsum);
    } else {
        out_h_rows(out_w, out_b, ws_h, out, 10668 + (bid - 128) * 4, t);
    }
}

// ------- K4: attn out (blocks 0..3) ∥ out_h rows [21336,32000) -------
__global__ __launch_bounds__(256) void k_red(const float* __restrict__ escore,
                                             const float* __restrict__ denom,
                                             float* __restrict__ out_attn,
                                             const float* __restrict__ ws_h,
                                             const float* __restrict__ out_w,
                                             const float* __restrict__ out_b,
                                             float* __restrict__ out)
{
    const int t = threadIdx.x, bid = blockIdx.x;
    if (bid < 4) {
        const float inv = 1.f / denom[0];
        const int s = bid * 1024 + t * 4;
        const float4 e = *(const float4*)(escore + s);
        *(float4*)(out_attn + s) = make_float4(e.x * inv, e.y * inv, e.z * inv, e.w * inv);
    } else {
        out_h_rows(out_w, out_b, ws_h, out, 21336 + (bid - 4) * 4, t);
    }
}

// ------- K5: out[row] += (out_w[row,1024:2048] . rawctx) / denom -------
__global__ __launch_bounds__(256) void k_tail(const float* __restrict__ out_w,
                                              const float* __restrict__ ws_ctx,
                                              const float* __restrict__ denom,
                                              float* __restrict__ out)
{
    __shared__ float c[Hn];
    const int t = threadIdx.x;
    const float inv = 1.f / denom[0];
    ((float4*)c)[t] = ((const float4*)ws_ctx)[t];
    __syncthreads();
    const int wv = t >> 6, lane = t & 63;
    const int row = blockIdx.x * 4 + wv;
    const float* w = out_w + (size_t)row * (2 * Hn) + Hn;
    float acc = 0.f;
#pragma unroll
    for (int k = 0; k < 4; ++k) {
        const int idx = k * 256 + lane * 4;
        const float4 w4 = *(const float4*)(w + idx);
        acc += w4.x * c[idx] + w4.y * c[idx + 1] + w4.z * c[idx + 2] + w4.w * c[idx + 3];
    }
    acc = wave_reduce_sum(acc);
    if (lane == 0) out[row] += acc * inv;
}

extern "C" void kernel_launch(void* const* d_in, const int* in_sizes, int n_in,
                              void* d_out, int out_size, void* d_ws, size_t ws_size,
                              hipStream_t stream) {
    const int*   word   = (const int*)d_in[0];
    const float* h_last = (const float*)d_in[1];
    const float* enc    = (const float*)d_in[2];
    const float* emb    = (const float*)d_in[3];
    const float* w_ih   = (const float*)d_in[4];
    const float* w_hh   = (const float*)d_in[5];
    const float* b_ih   = (const float*)d_in[6];
    const float* b_hh   = (const float*)d_in[7];
    const float* attn_w = (const float*)d_in[8];
    /* d_in[9] attn_b: unused — uniform shift, softmax-invariant */
    const float* out_w  = (const float*)d_in[10];
    const float* out_b  = (const float*)d_in[11];
    float* out = (float*)d_out;
    float* ws  = (float*)d_ws;

    float* ws_h      = ws;          // 1024
    float* ws_ctx    = ws + 1024;   // 1024 raw ctx (atomic)
    float* ws_v      = ws + 2048;   // 1024
    float* ws_escore = ws + 3072;   // 4096
    float* ws_denom  = ws + 7168;   // 1
    float* out_h     = out + Vn;
    float* out_attn  = out + Vn + Hn;

    k_gru<<<Hn, 256, 0, stream>>>(word, emb, h_last, w_ih, w_hh, b_ih, b_hh,
                                  ws_h, ws_ctx, ws_denom, out_h);
    k_a<<<64 + 2667, 256, 0, stream>>>(attn_w, ws_h, ws_v, out_w, out_b, out);
    k_sctx<<<128 + 2667, 256, 0, stream>>>(enc, ws_v, ws_escore, ws_ctx, ws_denom,
                                           ws_h, out_w, out_b, out);
    k_red<<<4 + 2666, 256, 0, stream>>>(ws_escore, ws_denom, out_attn,
                                        ws_h, out_w, out_b, out);
    k_tail<<<Vn / 4, 256, 0, stream>>>(out_w, ws_ctx, ws_denom, out);
}